// Round 10
// baseline (142.291 us; speedup 1.0000x reference)
//
#include <hip/hip_runtime.h>

// LFMA adapter: out = x@W_base^T + b + x @ (alpha * Re(ifft2(scatter(c, mask_idx))))
// Factored: never materialize Delta_W.
//   X[t,k1] = sum_m x[t,m] e^{+2pi i m k1/4096}   (dft_rows_x; Hermitian: store k<=2048, bf16)
//   Y[t,k2] = sum_{nz (k1,k2,c)} c * X[t,k1]      (bucketed sparse spmm)
//   out2[t,n] = SCALE * Re( sum_k2 Y[t,k2] e^{+2pi i n k2/4096} )   (dft_rows_y, WRITES out)
// R10: spmm gathers via inline-asm global_load_dwordx2 (8 in flight; R7/R9 showed the
// compiler serializes source-level load groups at VGPR=32 regardless of launch_bounds).
// Ordering enforced by data-dependency: the s_waitcnt asm takes all 8 dests as "+v".
// Bucketing: deterministic two-pass (LDS histograms + column scan), no global atomics.
// Base GEMM: kc=8 K-split, dbuf LDS, issue-early/write-late pipeline; reduce_bias sums.

#define TWO_PI 6.28318530717958647692f
constexpr int NROW = 128;
constexpr float SCALE_A = 16.0f / 16777216.0f;
constexpr int NCHUNK = 256;
constexpr int KC = 8;

typedef unsigned short ushort_t;
using short8 = __attribute__((ext_vector_type(8))) short;
using f32x4  = __attribute__((ext_vector_type(4))) float;

__device__ __forceinline__ ushort_t f2bf(float f) {
  unsigned u = __float_as_uint(f);
  u = (u + 0x7FFFu + ((u >> 16) & 1u)) >> 16;   // RNE
  return (ushort_t)u;
}

// ---------------- Kernel A: XTb[k][t] packed bf16 complex, k in [0,2048] (Hermitian).
// grid (128, 2): block qi handles k1 (mod-64 residue) in [qi*32, qi*32+32).
__global__ __launch_bounds__(1024) void dft_rows_x(const float* __restrict__ x,
                                                   unsigned* __restrict__ XTb) {
  __shared__ float xs[4096];
  __shared__ float br[2048], bi[2048];
  __shared__ float2 w64[64];
  const int t = blockIdx.x, qi = blockIdx.y, tid = threadIdx.x;
  const float* xrow = x + (size_t)t * 4096;
#pragma unroll
  for (int l = 0; l < 4; ++l) xs[tid + 1024 * l] = xrow[tid + 1024 * l];
  if (tid < 64) {
    float s, c; __sincosf(TWO_PI * (float)tid * (1.0f / 64.0f), &s, &c);
    w64[tid] = make_float2(c, s);          // W64^j = e^{+2pi i j/64}
  }
  __syncthreads();
  // phase 1: B[m1][k1] for k1 in this block's residue range only
#pragma unroll
  for (int l = 0; l < 2; ++l) {
    int o = tid + 1024 * l, m1 = o >> 5, k1l = o & 31, k1 = qi * 32 + k1l;
    float ar = 0.f, ai = 0.f;
    for (int m2 = 0; m2 < 64; ++m2) {
      float xv = xs[m1 + (m2 << 6)];
      float2 w = w64[(m2 * k1) & 63];
      ar = fmaf(xv, w.x, ar); ai = fmaf(xv, w.y, ai);
    }
    float s, c; __sincosf((float)(m1 * k1) * (TWO_PI / 4096.0f), &s, &c);
    br[(m1 << 5) + k1l] = ar * c - ai * s;
    bi[(m1 << 5) + k1l] = ar * s + ai * c;
  }
  __syncthreads();
  // phase 2: k = k1 + 64*k2, k2 in [0,32) -> covers all k<2048 with this residue
  {
    const int k1l = tid & 31, k2 = tid >> 5;
    const int k = qi * 32 + k1l + (k2 << 6);
    float xr = 0.f, xi = 0.f;
    for (int m1 = 0; m1 < 64; ++m1) {
      float brv = br[(m1 << 5) + k1l], biv = bi[(m1 << 5) + k1l];
      float2 w = w64[(m1 * k2) & 63];
      xr += brv * w.x - biv * w.y;
      xi += brv * w.y + biv * w.x;
    }
    XTb[(size_t)k * NROW + t] = (unsigned)f2bf(xr) | ((unsigned)f2bf(xi) << 16);
    if (qi == 0 && tid == 0) {             // k = 2048: w64^(32*m1) = (-1)^m1
      float xr2 = 0.f, xi2 = 0.f;
      for (int m1 = 0; m1 < 64; ++m1) {
        float sgn = (m1 & 1) ? -1.f : 1.f;
        xr2 = fmaf(sgn, br[m1 << 5], xr2);
        xi2 = fmaf(sgn, bi[m1 << 5], xi2);
      }
      XTb[(size_t)2048 * NROW + t] = (unsigned)f2bf(xr2) | ((unsigned)f2bf(xi2) << 16);
    }
  }
}

// ---------------- S1: per-chunk LDS histogram of k2
__global__ __launch_bounds__(1024) void count_chunks(const int* __restrict__ idx, int K,
                                                     int chunk, int* __restrict__ cnt) {
  __shared__ int h[4096];
  const int c = blockIdx.x, tid = threadIdx.x;
#pragma unroll
  for (int l = 0; l < 4; ++l) h[tid + 1024 * l] = 0;
  __syncthreads();
  const int j0 = c * chunk, j1 = min(j0 + chunk, K);
  for (int j = j0 + tid; j < j1; j += 1024) atomicAdd(&h[idx[j] & 4095], 1);
  __syncthreads();
#pragma unroll
  for (int l = 0; l < 4; ++l) cnt[(size_t)c * 4096 + tid + 1024 * l] = h[tid + 1024 * l];
}

// ---------------- S2: per-column exclusive scan over chunks (in place) + totals
__global__ __launch_bounds__(256) void colscan(int* __restrict__ cnt, int* __restrict__ tot) {
  const int k2 = blockIdx.x * 256 + threadIdx.x;
  int run = 0;
  for (int c8 = 0; c8 < NCHUNK; c8 += 8) {
    int v[8];
#pragma unroll
    for (int i = 0; i < 8; ++i) v[i] = cnt[(size_t)(c8 + i) * 4096 + k2];
#pragma unroll
    for (int i = 0; i < 8; ++i) {
      cnt[(size_t)(c8 + i) * 4096 + k2] = run;
      run += v[i];
    }
  }
  tot[k2] = run;
}

// ---------------- B2: exclusive scan over 4096 totals (single block)
__global__ __launch_bounds__(1024) void scan4096(const int* __restrict__ count,
                                                 int* __restrict__ off) {
  __shared__ int s[4096];
  int tid = threadIdx.x;
#pragma unroll
  for (int l = 0; l < 4; ++l) s[tid + 1024 * l] = count[tid + 1024 * l];
  __syncthreads();
  for (int d = 1; d < 4096; d <<= 1) {
    int v[4];
#pragma unroll
    for (int l = 0; l < 4; ++l) {
      int i = tid + 1024 * l;
      v[l] = s[i] + ((i >= d) ? s[i - d] : 0);
    }
    __syncthreads();
#pragma unroll
    for (int l = 0; l < 4; ++l) s[tid + 1024 * l] = v[l];
    __syncthreads();
  }
#pragma unroll
  for (int l = 0; l < 4; ++l) {
    int i = tid + 1024 * l;
    off[i] = s[i] - count[i];
  }
}

// ---------------- S3: scatter with LDS-rank (no returning global atomics)
__global__ __launch_bounds__(1024) void scatter2(const int* __restrict__ idx,
                                                 const float* __restrict__ cre,
                                                 const float* __restrict__ cim, int K,
                                                 int chunk, const int* __restrict__ base,
                                                 const int* __restrict__ off,
                                                 uint2* __restrict__ bucket) {
  __shared__ int lbase[4096];
  __shared__ int lcur[4096];
  const int c = blockIdx.x, tid = threadIdx.x;
#pragma unroll
  for (int l = 0; l < 4; ++l) {
    int k2 = tid + 1024 * l;
    lbase[k2] = base[(size_t)c * 4096 + k2] + off[k2];
    lcur[k2] = 0;
  }
  __syncthreads();
  const int j0 = c * chunk, j1 = min(j0 + chunk, K);
  for (int j = j0 + tid; j < j1; j += 1024) {
    int p = idx[j];
    int k2 = p & 4095;
    int r = atomicAdd(&lcur[k2], 1);          // LDS atomic: fast
    unsigned cr = f2bf(cre[j]), ci = f2bf(cim[j]);
    bucket[lbase[k2] + r] = make_uint2((unsigned)(p >> 12) | (cr << 16), ci << 16);
  }
}

// ---------------- B4: Y[t][k2] = sum c * X[t,k1]. 2 waves per column, 2 cols/block.
// Inline-asm gather pipeline: 8 global_load_dwordx2 issued back-to-back, one
// s_waitcnt with all dests as "+v" operands (data-dep ordering), then 8x8 fma.
__global__ __launch_bounds__(256, 4) void spmm_col(const uint2* __restrict__ bucket,
                                                   const int* __restrict__ off,
                                                   const int* __restrict__ count,
                                                   const unsigned* __restrict__ XTb,
                                                   float2* __restrict__ Y) {
  __shared__ float4 red[2][64];
  const int lane = threadIdx.x & 63;
  const int wid = threadIdx.x >> 6;
  const int colsel = wid >> 1, half = wid & 1;
  const int k2 = blockIdx.x * 2 + colsel;
  const int s = off[k2], n = count[k2];
  const unsigned voff = lane * 8;           // byte offset within row
  float ar0 = 0.f, ai0 = 0.f, ar1 = 0.f, ai1 = 0.f;
  for (int c = half * 64; c < n; c += 128) {
    int idx = c + lane;
    uint2 ec = (idx < n) ? bucket[s + idx] : make_uint2(0u, 0u);
#pragma unroll
    for (int g = 0; g < 64; g += 8) {
      int crb[8], cib[8], negm[8];
      uint2 xv0, xv1, xv2, xv3, xv4, xv5, xv6, xv7;
      // scalar fold + issue 8 independent gathers (saddr form, uniform row base)
#pragma unroll
      for (int u = 0; u < 8; ++u) {
        int w0 = __builtin_amdgcn_readlane((int)ec.x, g + u);
        int w1 = __builtin_amdgcn_readlane((int)ec.y, g + u);
        int k1 = w0 & 0xfff;
        negm[u] = (k1 > 2048) ? (int)0x80000000 : 0;
        int r = (k1 > 2048) ? 4096 - k1 : k1;
        crb[u] = w0 & 0xffff0000;
        cib[u] = w1;
        const unsigned* p = XTb + (size_t)r * NROW;
        uint2* dst = (u == 0) ? &xv0 : (u == 1) ? &xv1 : (u == 2) ? &xv2 :
                     (u == 3) ? &xv3 : (u == 4) ? &xv4 : (u == 5) ? &xv5 :
                     (u == 6) ? &xv6 : &xv7;
        asm volatile("global_load_dwordx2 %0, %1, %2"
                     : "=v"(*dst) : "v"(voff), "s"(p) : "memory");
      }
      // wait for all 8; "+v" on every dest makes post-wait uses depend on this asm
      asm volatile("s_waitcnt vmcnt(0)"
                   : "+v"(xv0), "+v"(xv1), "+v"(xv2), "+v"(xv3),
                     "+v"(xv4), "+v"(xv5), "+v"(xv6), "+v"(xv7) :: "memory");
      __builtin_amdgcn_sched_barrier(0);
#pragma unroll
      for (int u = 0; u < 8; ++u) {
        uint2 xv = (u == 0) ? xv0 : (u == 1) ? xv1 : (u == 2) ? xv2 :
                   (u == 3) ? xv3 : (u == 4) ? xv4 : (u == 5) ? xv5 :
                   (u == 6) ? xv6 : xv7;
        float cr  = __int_as_float(crb[u]);
        float ci  = __int_as_float(cib[u]);
        float crs = __int_as_float(crb[u] ^ negm[u]);
        float cis = __int_as_float(cib[u] ^ negm[u]);
        float xr0 = __int_as_float(xv.x << 16);
        float xi0 = __int_as_float(xv.x & 0xffff0000u);
        float xr1 = __int_as_float(xv.y << 16);
        float xi1 = __int_as_float(xv.y & 0xffff0000u);
        ar0 = fmaf(cr, xr0, ar0);  ar0 = fmaf(-cis, xi0, ar0);
        ai0 = fmaf(crs, xi0, ai0); ai0 = fmaf(ci, xr0, ai0);
        ar1 = fmaf(cr, xr1, ar1);  ar1 = fmaf(-cis, xi1, ar1);
        ai1 = fmaf(crs, xi1, ai1); ai1 = fmaf(ci, xr1, ai1);
      }
    }
  }
  if (half == 1) red[colsel][lane] = make_float4(ar0, ai0, ar1, ai1);
  __syncthreads();
  if (half == 0) {
    float4 o = red[colsel][lane];
    ar0 += o.x; ai0 += o.y; ar1 += o.z; ai1 += o.w;
    Y[(size_t)(2 * lane) * 4096 + k2]     = make_float2(ar0, ai0);
    Y[(size_t)(2 * lane + 1) * 4096 + k2] = make_float2(ar1, ai1);
  }
}

// ---------------- Kernel C: out[t][n] = SCALE * Re(DFT-4096 of Y row). grid (128,2).
// Block qi handles n1 (mod-64 residue) in [qi*32, qi*32+32). WRITES out.
__global__ __launch_bounds__(1024) void dft_rows_y(const float2* __restrict__ Y,
                                                   float* __restrict__ out) {
  __shared__ float ysr[4096], ysi[4096];
  __shared__ float br[2048], bi[2048];
  __shared__ float2 w64[64];
  const int t = blockIdx.x, qi = blockIdx.y, tid = threadIdx.x;
  const float2* yrow = Y + (size_t)t * 4096;
#pragma unroll
  for (int l = 0; l < 4; ++l) {
    float2 v = yrow[tid + 1024 * l];
    ysr[tid + 1024 * l] = v.x; ysi[tid + 1024 * l] = v.y;
  }
  if (tid < 64) {
    float s, c; __sincosf(TWO_PI * (float)tid * (1.0f / 64.0f), &s, &c);
    w64[tid] = make_float2(c, s);
  }
  __syncthreads();
  // phase 1: B[a][n1] for n1 in this block's residue range
#pragma unroll
  for (int l = 0; l < 2; ++l) {
    int o = tid + 1024 * l, a = o >> 5, n1l = o & 31, n1 = qi * 32 + n1l;
    float ar = 0.f, ai = 0.f;
    for (int b = 0; b < 64; ++b) {
      float yr = ysr[a + (b << 6)], yi = ysi[a + (b << 6)];
      float2 w = w64[(n1 * b) & 63];
      ar += yr * w.x - yi * w.y;
      ai += yr * w.y + yi * w.x;
    }
    float s, c; __sincosf((float)(n1 * a) * (TWO_PI / 4096.0f), &s, &c);
    br[(a << 5) + n1l] = ar * c - ai * s;
    bi[(a << 5) + n1l] = ar * s + ai * c;
  }
  __syncthreads();
  // phase 2: n = n1 + 64*n2, n2 in [0,64)
  float* orow = out + (size_t)t * 4096;
  const int n1l = tid & 31;
  const int n1 = qi * 32 + n1l;
#pragma unroll
  for (int l = 0; l < 2; ++l) {
    int n2 = (tid >> 5) + 32 * l;
    float acc = 0.f;
    for (int a = 0; a < 64; ++a) {
      float brv = br[(a << 5) + n1l], biv = bi[(a << 5) + n1l];
      float2 w = w64[(n2 * a) & 63];
      acc += brv * w.x - biv * w.y;
    }
    orow[n1 + (n2 << 6)] = acc * SCALE_A;
  }
}

// ---------------- x -> bf16 pre-convert
__global__ __launch_bounds__(256) void xcvt(const float* __restrict__ x,
                                            ushort_t* __restrict__ xbf) {
  size_t e = ((size_t)blockIdx.x * 256 + threadIdx.x) * 4;
  float4 v = *(const float4*)(x + e);
  unsigned lo = (unsigned)f2bf(v.x) | ((unsigned)f2bf(v.y) << 16);
  unsigned hi = (unsigned)f2bf(v.z) | ((unsigned)f2bf(v.w) << 16);
  *(uint2*)(xbf + e) = make_uint2(lo, hi);
}

// ---------------- base GEMM partials: part[kc][t][f], tile 128(t) x 64(f) x 64(k)
__global__ __launch_bounds__(256) void gemm_mfma_partial(const ushort_t* __restrict__ xbf,
                                                         const float* __restrict__ W,
                                                         float* __restrict__ part) {
  __shared__ ushort_t xs[2][128 * 64];
  __shared__ ushort_t wsl[2][64 * 64];
  const int f0 = blockIdx.x * 64;
  const int kc = blockIdx.y;
  const int tid = threadIdx.x;
  const int w = tid >> 6, lane = tid & 63;

  f32x4 acc[2][4];
#pragma unroll
  for (int i = 0; i < 2; ++i)
#pragma unroll
    for (int j = 0; j < 4; ++j) acc[i][j] = (f32x4){0.f, 0.f, 0.f, 0.f};

  uint4 rx[4];
  float4 rwa[2], rwb[2];
  const int kbeg = kc * 512;

#pragma unroll
  for (int l = 0; l < 4; ++l) {
    int s = tid + 256 * l, r = s >> 3, ks = s & 7;
    rx[l] = *(const uint4*)(xbf + (size_t)r * 4096 + kbeg + ks * 8);
  }
#pragma unroll
  for (int l = 0; l < 2; ++l) {
    int s = tid + 256 * l, r = s >> 3, ks = s & 7;
    const float* wp = W + (size_t)(f0 + r) * 4096 + kbeg + ks * 8;
    rwa[l] = *(const float4*)(wp);
    rwb[l] = *(const float4*)(wp + 4);
  }

  int cur = 0;
  for (int st = 0; st < 8; ++st) {
#pragma unroll
    for (int l = 0; l < 4; ++l) {
      int s = tid + 256 * l, r = s >> 3, ks = s & 7;
      *(uint4*)(&xs[cur][r * 64 + ((ks ^ (r & 7)) << 3)]) = rx[l];
    }
#pragma unroll
    for (int l = 0; l < 2; ++l) {
      int s = tid + 256 * l, r = s >> 3, ks = s & 7;
      uint4 pk;
      pk.x = (unsigned)f2bf(rwa[l].x) | ((unsigned)f2bf(rwa[l].y) << 16);
      pk.y = (unsigned)f2bf(rwa[l].z) | ((unsigned)f2bf(rwa[l].w) << 16);
      pk.z = (unsigned)f2bf(rwb[l].x) | ((unsigned)f2bf(rwb[l].y) << 16);
      pk.w = (unsigned)f2bf(rwb[l].z) | ((unsigned)f2bf(rwb[l].w) << 16);
      *(uint4*)(&wsl[cur][r * 64 + ((ks ^ (r & 7)) << 3)]) = pk;
    }
    __syncthreads();
    if (st < 7) {
      const int k0 = kbeg + (st + 1) * 64;
#pragma unroll
      for (int l = 0; l < 4; ++l) {
        int s = tid + 256 * l, r = s >> 3, ks = s & 7;
        rx[l] = *(const uint4*)(xbf + (size_t)r * 4096 + k0 + ks * 8);
      }
#pragma unroll
      for (int l = 0; l < 2; ++l) {
        int s = tid + 256 * l, r = s >> 3, ks = s & 7;
        const float* wp = W + (size_t)(f0 + r) * 4096 + k0 + ks * 8;
        rwa[l] = *(const float4*)(wp);
        rwb[l] = *(const float4*)(wp + 4);
      }
    }
#pragma unroll
    for (int kk = 0; kk < 2; ++kk) {
      int ksA = kk * 4 + (lane >> 4);
      short8 af[2], bfr[4];
#pragma unroll
      for (int mf = 0; mf < 2; ++mf) {
        int ra = w * 32 + mf * 16 + (lane & 15);
        af[mf] = *(const short8*)(&xs[cur][ra * 64 + ((ksA ^ (ra & 7)) << 3)]);
      }
#pragma unroll
      for (int nf = 0; nf < 4; ++nf) {
        int rb = nf * 16 + (lane & 15);
        bfr[nf] = *(const short8*)(&wsl[cur][rb * 64 + ((ksA ^ (rb & 7)) << 3)]);
      }
#pragma unroll
      for (int mf = 0; mf < 2; ++mf)
#pragma unroll
        for (int nf = 0; nf < 4; ++nf)
          acc[mf][nf] = __builtin_amdgcn_mfma_f32_16x16x32_bf16(af[mf], bfr[nf], acc[mf][nf], 0, 0, 0);
    }
    cur ^= 1;
  }
  float* pb = part + ((size_t)kc << 19);
#pragma unroll
  for (int mf = 0; mf < 2; ++mf)
#pragma unroll
    for (int nf = 0; nf < 4; ++nf)
#pragma unroll
      for (int reg = 0; reg < 4; ++reg) {
        int row = w * 32 + mf * 16 + (lane >> 4) * 4 + reg;
        int col = f0 + nf * 16 + (lane & 15);
        pb[(size_t)row * 4096 + col] = acc[mf][nf][reg];
      }
}

// ---------------- out += bias + sum of KC partials (out already holds dft_y result)
__global__ __launch_bounds__(256) void reduce_bias(const float* __restrict__ part,
                                                   const float* __restrict__ b,
                                                   float* __restrict__ out) {
  size_t e = ((size_t)blockIdx.x * 256 + threadIdx.x) * 4;
  int f = (int)(e & 4095);
  float4 o  = *(const float4*)(out + e);
  float4 bb = *(const float4*)(b + f);
  float sx = o.x + bb.x, sy = o.y + bb.y, sz = o.z + bb.z, sw = o.w + bb.w;
#pragma unroll
  for (int i = 0; i < KC; ++i) {
    float4 v = *(const float4*)(part + e + ((size_t)i << 19));
    sx += v.x; sy += v.y; sz += v.z; sw += v.w;
  }
  *(float4*)(out + e) = make_float4(sx, sy, sz, sw);
}

extern "C" void kernel_launch(void* const* d_in, const int* in_sizes, int n_in,
                              void* d_out, int out_size, void* d_ws, size_t ws_size,
                              hipStream_t stream) {
  const float* x   = (const float*)d_in[0];
  const float* W   = (const float*)d_in[1];
  const float* b   = (const float*)d_in[2];
  const float* cre = (const float*)d_in[3];
  const float* cim = (const float*)d_in[4];
  const int* midx  = (const int*)d_in[5];
  const int K = in_sizes[3];
  float* out = (float*)d_out;
  const int chunk = (K + NCHUNK - 1) / NCHUNK;

  char* ws = (char*)d_ws;
  unsigned* XTb  = (unsigned*)(ws);                        // ~1.05 MB
  float2* Y      = (float2*)(ws + (size_t)(2 << 20));      // 4 MB
  uint2* bucket  = (uint2*)(ws + (size_t)(6 << 20));       // K*8 ~= 6.7 MB (ends <13M)
  int* cnt       = (int*)(ws + (size_t)(13 << 20));        // 4 MB (ends 17M)
  char* meta     = ws + (size_t)(17 << 20);                // tot/off 32 KB
  int* tot = (int*)(meta);
  int* off = (int*)(meta + 16384);
  ushort_t* xbf  = (ushort_t*)(ws + (size_t)(18 << 20));   // 1 MB (ends 19M)
  float* part    = (float*)(ws + (size_t)(2 << 20));       // KC*2MB = 16 MB (ends 18M);
  // part ALIASES Y/bucket/cnt/meta — all fully consumed before gemm runs.

  xcvt<<<512, 256, 0, stream>>>(x, xbf);
  dft_rows_x<<<dim3(NROW, 2), 1024, 0, stream>>>(x, XTb);
  count_chunks<<<NCHUNK, 1024, 0, stream>>>(midx, K, chunk, cnt);
  colscan<<<16, 256, 0, stream>>>(cnt, tot);
  scan4096<<<1, 1024, 0, stream>>>(tot, off);
  scatter2<<<NCHUNK, 1024, 0, stream>>>(midx, cre, cim, K, chunk, cnt, off, bucket);
  spmm_col<<<2048, 256, 0, stream>>>(bucket, off, tot, XTb, Y);
  dft_rows_y<<<dim3(NROW, 2), 1024, 0, stream>>>(Y, out);      // writes out2
  gemm_mfma_partial<<<dim3(64, KC), 256, 0, stream>>>(xbf, W, part);
  reduce_bias<<<512, 256, 0, stream>>>(part, b, out);          // out += b + sum(part)
}

// Round 11
// 140.622 us; speedup vs baseline: 1.0119x; 1.0119x over previous
//
#include <hip/hip_runtime.h>

// LFMA adapter: out = x@W_base^T + b + x @ (alpha * Re(ifft2(scatter(c, mask_idx))))
// Factored: never materialize Delta_W.
//   X[t,k1] = sum_m x[t,m] e^{+2pi i m k1/4096}   (dft_rows_x; Hermitian: store k<=2048, bf16)
//   Y[t,k2] = sum_{nz (k1,k2,c)} c * X[t,k1]      (bucketed sparse spmm)
//   out2[t,n] = SCALE * Re( sum_k2 Y[t,k2] e^{+2pi i n k2/4096} )   (dft_rows_y, WRITES out)
// R11: spmm compute via v_dot2_f32_bf16 (XTb words are already packed bf16 pairs; the
// packed coefficient words are built on the SALU). R10 proved the 43us was VALU-issue
// bound (~33 inst/entry), not latency: dot2 cuts it to ~8/entry.
// Bucketing: deterministic two-pass (LDS histograms + column scan), no global atomics.
// Base GEMM: kc=8 K-split, dbuf LDS, issue-early/write-late pipeline; reduce_bias sums.

#define TWO_PI 6.28318530717958647692f
constexpr int NROW = 128;
constexpr float SCALE_A = 16.0f / 16777216.0f;
constexpr int NCHUNK = 256;
constexpr int KC = 8;

typedef unsigned short ushort_t;
using short8 = __attribute__((ext_vector_type(8))) short;
using f32x4  = __attribute__((ext_vector_type(4))) float;

__device__ __forceinline__ ushort_t f2bf(float f) {
  unsigned u = __float_as_uint(f);
  u = (u + 0x7FFFu + ((u >> 16) & 1u)) >> 16;   // RNE
  return (ushort_t)u;
}

// ---------------- Kernel A: XTb[k][t] packed bf16 complex, k in [0,2048] (Hermitian).
// grid (128, 2): block qi handles k1 (mod-64 residue) in [qi*32, qi*32+32).
__global__ __launch_bounds__(1024) void dft_rows_x(const float* __restrict__ x,
                                                   unsigned* __restrict__ XTb) {
  __shared__ float xs[4096];
  __shared__ float br[2048], bi[2048];
  __shared__ float2 w64[64];
  const int t = blockIdx.x, qi = blockIdx.y, tid = threadIdx.x;
  const float* xrow = x + (size_t)t * 4096;
#pragma unroll
  for (int l = 0; l < 4; ++l) xs[tid + 1024 * l] = xrow[tid + 1024 * l];
  if (tid < 64) {
    float s, c; __sincosf(TWO_PI * (float)tid * (1.0f / 64.0f), &s, &c);
    w64[tid] = make_float2(c, s);          // W64^j = e^{+2pi i j/64}
  }
  __syncthreads();
  // phase 1: B[m1][k1] for k1 in this block's residue range only
#pragma unroll
  for (int l = 0; l < 2; ++l) {
    int o = tid + 1024 * l, m1 = o >> 5, k1l = o & 31, k1 = qi * 32 + k1l;
    float ar = 0.f, ai = 0.f;
    for (int m2 = 0; m2 < 64; ++m2) {
      float xv = xs[m1 + (m2 << 6)];
      float2 w = w64[(m2 * k1) & 63];
      ar = fmaf(xv, w.x, ar); ai = fmaf(xv, w.y, ai);
    }
    float s, c; __sincosf((float)(m1 * k1) * (TWO_PI / 4096.0f), &s, &c);
    br[(m1 << 5) + k1l] = ar * c - ai * s;
    bi[(m1 << 5) + k1l] = ar * s + ai * c;
  }
  __syncthreads();
  // phase 2: k = k1 + 64*k2, k2 in [0,32) -> covers all k<2048 with this residue
  {
    const int k1l = tid & 31, k2 = tid >> 5;
    const int k = qi * 32 + k1l + (k2 << 6);
    float xr = 0.f, xi = 0.f;
    for (int m1 = 0; m1 < 64; ++m1) {
      float brv = br[(m1 << 5) + k1l], biv = bi[(m1 << 5) + k1l];
      float2 w = w64[(m1 * k2) & 63];
      xr += brv * w.x - biv * w.y;
      xi += brv * w.y + biv * w.x;
    }
    XTb[(size_t)k * NROW + t] = (unsigned)f2bf(xr) | ((unsigned)f2bf(xi) << 16);
    if (qi == 0 && tid == 0) {             // k = 2048: w64^(32*m1) = (-1)^m1
      float xr2 = 0.f, xi2 = 0.f;
      for (int m1 = 0; m1 < 64; ++m1) {
        float sgn = (m1 & 1) ? -1.f : 1.f;
        xr2 = fmaf(sgn, br[m1 << 5], xr2);
        xi2 = fmaf(sgn, bi[m1 << 5], xi2);
      }
      XTb[(size_t)2048 * NROW + t] = (unsigned)f2bf(xr2) | ((unsigned)f2bf(xi2) << 16);
    }
  }
}

// ---------------- S1: per-chunk LDS histogram of k2
__global__ __launch_bounds__(1024) void count_chunks(const int* __restrict__ idx, int K,
                                                     int chunk, int* __restrict__ cnt) {
  __shared__ int h[4096];
  const int c = blockIdx.x, tid = threadIdx.x;
#pragma unroll
  for (int l = 0; l < 4; ++l) h[tid + 1024 * l] = 0;
  __syncthreads();
  const int j0 = c * chunk, j1 = min(j0 + chunk, K);
  for (int j = j0 + tid; j < j1; j += 1024) atomicAdd(&h[idx[j] & 4095], 1);
  __syncthreads();
#pragma unroll
  for (int l = 0; l < 4; ++l) cnt[(size_t)c * 4096 + tid + 1024 * l] = h[tid + 1024 * l];
}

// ---------------- S2: per-column exclusive scan over chunks (in place) + totals
__global__ __launch_bounds__(256) void colscan(int* __restrict__ cnt, int* __restrict__ tot) {
  const int k2 = blockIdx.x * 256 + threadIdx.x;
  int run = 0;
  for (int c8 = 0; c8 < NCHUNK; c8 += 8) {
    int v[8];
#pragma unroll
    for (int i = 0; i < 8; ++i) v[i] = cnt[(size_t)(c8 + i) * 4096 + k2];
#pragma unroll
    for (int i = 0; i < 8; ++i) {
      cnt[(size_t)(c8 + i) * 4096 + k2] = run;
      run += v[i];
    }
  }
  tot[k2] = run;
}

// ---------------- B2: exclusive scan over 4096 totals (single block)
__global__ __launch_bounds__(1024) void scan4096(const int* __restrict__ count,
                                                 int* __restrict__ off) {
  __shared__ int s[4096];
  int tid = threadIdx.x;
#pragma unroll
  for (int l = 0; l < 4; ++l) s[tid + 1024 * l] = count[tid + 1024 * l];
  __syncthreads();
  for (int d = 1; d < 4096; d <<= 1) {
    int v[4];
#pragma unroll
    for (int l = 0; l < 4; ++l) {
      int i = tid + 1024 * l;
      v[l] = s[i] + ((i >= d) ? s[i - d] : 0);
    }
    __syncthreads();
#pragma unroll
    for (int l = 0; l < 4; ++l) s[tid + 1024 * l] = v[l];
    __syncthreads();
  }
#pragma unroll
  for (int l = 0; l < 4; ++l) {
    int i = tid + 1024 * l;
    off[i] = s[i] - count[i];
  }
}

// ---------------- S3: scatter with LDS-rank (no returning global atomics)
__global__ __launch_bounds__(1024) void scatter2(const int* __restrict__ idx,
                                                 const float* __restrict__ cre,
                                                 const float* __restrict__ cim, int K,
                                                 int chunk, const int* __restrict__ base,
                                                 const int* __restrict__ off,
                                                 uint2* __restrict__ bucket) {
  __shared__ int lbase[4096];
  __shared__ int lcur[4096];
  const int c = blockIdx.x, tid = threadIdx.x;
#pragma unroll
  for (int l = 0; l < 4; ++l) {
    int k2 = tid + 1024 * l;
    lbase[k2] = base[(size_t)c * 4096 + k2] + off[k2];
    lcur[k2] = 0;
  }
  __syncthreads();
  const int j0 = c * chunk, j1 = min(j0 + chunk, K);
  for (int j = j0 + tid; j < j1; j += 1024) {
    int p = idx[j];
    int k2 = p & 4095;
    int r = atomicAdd(&lcur[k2], 1);          // LDS atomic: fast
    unsigned cr = f2bf(cre[j]), ci = f2bf(cim[j]);
    bucket[lbase[k2] + r] = make_uint2((unsigned)(p >> 12) | (cr << 16), ci << 16);
  }
}

// ---------------- B4: Y[t][k2] = sum c * X[t,k1]. 2 waves per column, 2 cols/block.
// Asm gather pipeline (8 in flight) + v_dot2_f32_bf16 compute:
//   ar += dot2((cr, -(ci^cj)), (xr,xi));  ai += dot2((ci, cr^cj), (xr,xi))
// where cj flips the bf16 sign for Hermitian-conjugate rows. Packed A/B built on SALU.
__global__ __launch_bounds__(256, 4) void spmm_col(const uint2* __restrict__ bucket,
                                                   const int* __restrict__ off,
                                                   const int* __restrict__ count,
                                                   const unsigned* __restrict__ XTb,
                                                   float2* __restrict__ Y) {
  __shared__ float4 red[2][64];
  const int lane = threadIdx.x & 63;
  const int wid = threadIdx.x >> 6;
  const int colsel = wid >> 1, half = wid & 1;
  const int k2 = blockIdx.x * 2 + colsel;
  const int s = off[k2], n = count[k2];
  const unsigned voff = lane * 8;           // byte offset within row
  float ar0 = 0.f, ai0 = 0.f, ar1 = 0.f, ai1 = 0.f;
  for (int c = half * 64; c < n; c += 128) {
    int idx = c + lane;
    uint2 ec = (idx < n) ? bucket[s + idx] : make_uint2(0u, 0u);
#pragma unroll
    for (int g = 0; g < 64; g += 8) {
      unsigned Ap[8], Bp[8];
      uint2 xv0, xv1, xv2, xv3, xv4, xv5, xv6, xv7;
      // scalar fold + issue 8 independent gathers (saddr form, uniform row base)
#pragma unroll
      for (int u = 0; u < 8; ++u) {
        unsigned w0 = (unsigned)__builtin_amdgcn_readlane((int)ec.x, g + u);
        unsigned w1 = (unsigned)__builtin_amdgcn_readlane((int)ec.y, g + u);
        int k1 = (int)(w0 & 0xfffu);
        unsigned cj = (k1 > 2048) ? 0x8000u : 0u;
        int r = (k1 > 2048) ? 4096 - k1 : k1;
        unsigned cr16 = w0 >> 16;
        unsigned ci16 = w1 >> 16;
        Ap[u] = cr16 | ((ci16 ^ 0x8000u ^ cj) << 16);   // (cr, -(+-ci))
        Bp[u] = ci16 | ((cr16 ^ cj) << 16);             // (ci, +-cr)
        const unsigned* p = XTb + (size_t)r * NROW;
        uint2* dst = (u == 0) ? &xv0 : (u == 1) ? &xv1 : (u == 2) ? &xv2 :
                     (u == 3) ? &xv3 : (u == 4) ? &xv4 : (u == 5) ? &xv5 :
                     (u == 6) ? &xv6 : &xv7;
        asm volatile("global_load_dwordx2 %0, %1, %2"
                     : "=v"(*dst) : "v"(voff), "s"(p) : "memory");
      }
      asm volatile("s_waitcnt vmcnt(0)"
                   : "+v"(xv0), "+v"(xv1), "+v"(xv2), "+v"(xv3),
                     "+v"(xv4), "+v"(xv5), "+v"(xv6), "+v"(xv7) :: "memory");
      __builtin_amdgcn_sched_barrier(0);
#pragma unroll
      for (int u = 0; u < 8; ++u) {
        uint2 xv = (u == 0) ? xv0 : (u == 1) ? xv1 : (u == 2) ? xv2 :
                   (u == 3) ? xv3 : (u == 4) ? xv4 : (u == 5) ? xv5 :
                   (u == 6) ? xv6 : xv7;
        asm("v_dot2_f32_bf16 %0, %1, %2, %0" : "+v"(ar0) : "v"(Ap[u]), "v"(xv.x));
        asm("v_dot2_f32_bf16 %0, %1, %2, %0" : "+v"(ai0) : "v"(Bp[u]), "v"(xv.x));
        asm("v_dot2_f32_bf16 %0, %1, %2, %0" : "+v"(ar1) : "v"(Ap[u]), "v"(xv.y));
        asm("v_dot2_f32_bf16 %0, %1, %2, %0" : "+v"(ai1) : "v"(Bp[u]), "v"(xv.y));
      }
    }
  }
  if (half == 1) red[colsel][lane] = make_float4(ar0, ai0, ar1, ai1);
  __syncthreads();
  if (half == 0) {
    float4 o = red[colsel][lane];
    ar0 += o.x; ai0 += o.y; ar1 += o.z; ai1 += o.w;
    Y[(size_t)(2 * lane) * 4096 + k2]     = make_float2(ar0, ai0);
    Y[(size_t)(2 * lane + 1) * 4096 + k2] = make_float2(ar1, ai1);
  }
}

// ---------------- Kernel C: out[t][n] = SCALE * Re(DFT-4096 of Y row). grid (128,2).
// Block qi handles n1 (mod-64 residue) in [qi*32, qi*32+32). WRITES out.
__global__ __launch_bounds__(1024) void dft_rows_y(const float2* __restrict__ Y,
                                                   float* __restrict__ out) {
  __shared__ float ysr[4096], ysi[4096];
  __shared__ float br[2048], bi[2048];
  __shared__ float2 w64[64];
  const int t = blockIdx.x, qi = blockIdx.y, tid = threadIdx.x;
  const float2* yrow = Y + (size_t)t * 4096;
#pragma unroll
  for (int l = 0; l < 4; ++l) {
    float2 v = yrow[tid + 1024 * l];
    ysr[tid + 1024 * l] = v.x; ysi[tid + 1024 * l] = v.y;
  }
  if (tid < 64) {
    float s, c; __sincosf(TWO_PI * (float)tid * (1.0f / 64.0f), &s, &c);
    w64[tid] = make_float2(c, s);
  }
  __syncthreads();
  // phase 1: B[a][n1] for n1 in this block's residue range
#pragma unroll
  for (int l = 0; l < 2; ++l) {
    int o = tid + 1024 * l, a = o >> 5, n1l = o & 31, n1 = qi * 32 + n1l;
    float ar = 0.f, ai = 0.f;
    for (int b = 0; b < 64; ++b) {
      float yr = ysr[a + (b << 6)], yi = ysi[a + (b << 6)];
      float2 w = w64[(n1 * b) & 63];
      ar += yr * w.x - yi * w.y;
      ai += yr * w.y + yi * w.x;
    }
    float s, c; __sincosf((float)(n1 * a) * (TWO_PI / 4096.0f), &s, &c);
    br[(a << 5) + n1l] = ar * c - ai * s;
    bi[(a << 5) + n1l] = ar * s + ai * c;
  }
  __syncthreads();
  // phase 2: n = n1 + 64*n2, n2 in [0,64)
  float* orow = out + (size_t)t * 4096;
  const int n1l = tid & 31;
  const int n1 = qi * 32 + n1l;
#pragma unroll
  for (int l = 0; l < 2; ++l) {
    int n2 = (tid >> 5) + 32 * l;
    float acc = 0.f;
    for (int a = 0; a < 64; ++a) {
      float brv = br[(a << 5) + n1l], biv = bi[(a << 5) + n1l];
      float2 w = w64[(n2 * a) & 63];
      acc += brv * w.x - biv * w.y;
    }
    orow[n1 + (n2 << 6)] = acc * SCALE_A;
  }
}

// ---------------- x -> bf16 pre-convert
__global__ __launch_bounds__(256) void xcvt(const float* __restrict__ x,
                                            ushort_t* __restrict__ xbf) {
  size_t e = ((size_t)blockIdx.x * 256 + threadIdx.x) * 4;
  float4 v = *(const float4*)(x + e);
  unsigned lo = (unsigned)f2bf(v.x) | ((unsigned)f2bf(v.y) << 16);
  unsigned hi = (unsigned)f2bf(v.z) | ((unsigned)f2bf(v.w) << 16);
  *(uint2*)(xbf + e) = make_uint2(lo, hi);
}

// ---------------- base GEMM partials: part[kc][t][f], tile 128(t) x 64(f) x 64(k)
__global__ __launch_bounds__(256) void gemm_mfma_partial(const ushort_t* __restrict__ xbf,
                                                         const float* __restrict__ W,
                                                         float* __restrict__ part) {
  __shared__ ushort_t xs[2][128 * 64];
  __shared__ ushort_t wsl[2][64 * 64];
  const int f0 = blockIdx.x * 64;
  const int kc = blockIdx.y;
  const int tid = threadIdx.x;
  const int w = tid >> 6, lane = tid & 63;

  f32x4 acc[2][4];
#pragma unroll
  for (int i = 0; i < 2; ++i)
#pragma unroll
    for (int j = 0; j < 4; ++j) acc[i][j] = (f32x4){0.f, 0.f, 0.f, 0.f};

  uint4 rx[4];
  float4 rwa[2], rwb[2];
  const int kbeg = kc * 512;

#pragma unroll
  for (int l = 0; l < 4; ++l) {
    int s = tid + 256 * l, r = s >> 3, ks = s & 7;
    rx[l] = *(const uint4*)(xbf + (size_t)r * 4096 + kbeg + ks * 8);
  }
#pragma unroll
  for (int l = 0; l < 2; ++l) {
    int s = tid + 256 * l, r = s >> 3, ks = s & 7;
    const float* wp = W + (size_t)(f0 + r) * 4096 + kbeg + ks * 8;
    rwa[l] = *(const float4*)(wp);
    rwb[l] = *(const float4*)(wp + 4);
  }

  int cur = 0;
  for (int st = 0; st < 8; ++st) {
#pragma unroll
    for (int l = 0; l < 4; ++l) {
      int s = tid + 256 * l, r = s >> 3, ks = s & 7;
      *(uint4*)(&xs[cur][r * 64 + ((ks ^ (r & 7)) << 3)]) = rx[l];
    }
#pragma unroll
    for (int l = 0; l < 2; ++l) {
      int s = tid + 256 * l, r = s >> 3, ks = s & 7;
      uint4 pk;
      pk.x = (unsigned)f2bf(rwa[l].x) | ((unsigned)f2bf(rwa[l].y) << 16);
      pk.y = (unsigned)f2bf(rwa[l].z) | ((unsigned)f2bf(rwa[l].w) << 16);
      pk.z = (unsigned)f2bf(rwb[l].x) | ((unsigned)f2bf(rwb[l].y) << 16);
      pk.w = (unsigned)f2bf(rwb[l].z) | ((unsigned)f2bf(rwb[l].w) << 16);
      *(uint4*)(&wsl[cur][r * 64 + ((ks ^ (r & 7)) << 3)]) = pk;
    }
    __syncthreads();
    if (st < 7) {
      const int k0 = kbeg + (st + 1) * 64;
#pragma unroll
      for (int l = 0; l < 4; ++l) {
        int s = tid + 256 * l, r = s >> 3, ks = s & 7;
        rx[l] = *(const uint4*)(xbf + (size_t)r * 4096 + k0 + ks * 8);
      }
#pragma unroll
      for (int l = 0; l < 2; ++l) {
        int s = tid + 256 * l, r = s >> 3, ks = s & 7;
        const float* wp = W + (size_t)(f0 + r) * 4096 + k0 + ks * 8;
        rwa[l] = *(const float4*)(wp);
        rwb[l] = *(const float4*)(wp + 4);
      }
    }
#pragma unroll
    for (int kk = 0; kk < 2; ++kk) {
      int ksA = kk * 4 + (lane >> 4);
      short8 af[2], bfr[4];
#pragma unroll
      for (int mf = 0; mf < 2; ++mf) {
        int ra = w * 32 + mf * 16 + (lane & 15);
        af[mf] = *(const short8*)(&xs[cur][ra * 64 + ((ksA ^ (ra & 7)) << 3)]);
      }
#pragma unroll
      for (int nf = 0; nf < 4; ++nf) {
        int rb = nf * 16 + (lane & 15);
        bfr[nf] = *(const short8*)(&wsl[cur][rb * 64 + ((ksA ^ (rb & 7)) << 3)]);
      }
#pragma unroll
      for (int mf = 0; mf < 2; ++mf)
#pragma unroll
        for (int nf = 0; nf < 4; ++nf)
          acc[mf][nf] = __builtin_amdgcn_mfma_f32_16x16x32_bf16(af[mf], bfr[nf], acc[mf][nf], 0, 0, 0);
    }
    cur ^= 1;
  }
  float* pb = part + ((size_t)kc << 19);
#pragma unroll
  for (int mf = 0; mf < 2; ++mf)
#pragma unroll
    for (int nf = 0; nf < 4; ++nf)
#pragma unroll
      for (int reg = 0; reg < 4; ++reg) {
        int row = w * 32 + mf * 16 + (lane >> 4) * 4 + reg;
        int col = f0 + nf * 16 + (lane & 15);
        pb[(size_t)row * 4096 + col] = acc[mf][nf][reg];
      }
}

// ---------------- out += bias + sum of KC partials (out already holds dft_y result)
__global__ __launch_bounds__(256) void reduce_bias(const float* __restrict__ part,
                                                   const float* __restrict__ b,
                                                   float* __restrict__ out) {
  size_t e = ((size_t)blockIdx.x * 256 + threadIdx.x) * 4;
  int f = (int)(e & 4095);
  float4 o  = *(const float4*)(out + e);
  float4 bb = *(const float4*)(b + f);
  float sx = o.x + bb.x, sy = o.y + bb.y, sz = o.z + bb.z, sw = o.w + bb.w;
#pragma unroll
  for (int i = 0; i < KC; ++i) {
    float4 v = *(const float4*)(part + e + ((size_t)i << 19));
    sx += v.x; sy += v.y; sz += v.z; sw += v.w;
  }
  *(float4*)(out + e) = make_float4(sx, sy, sz, sw);
}

extern "C" void kernel_launch(void* const* d_in, const int* in_sizes, int n_in,
                              void* d_out, int out_size, void* d_ws, size_t ws_size,
                              hipStream_t stream) {
  const float* x   = (const float*)d_in[0];
  const float* W   = (const float*)d_in[1];
  const float* b   = (const float*)d_in[2];
  const float* cre = (const float*)d_in[3];
  const float* cim = (const float*)d_in[4];
  const int* midx  = (const int*)d_in[5];
  const int K = in_sizes[3];
  float* out = (float*)d_out;
  const int chunk = (K + NCHUNK - 1) / NCHUNK;

  char* ws = (char*)d_ws;
  unsigned* XTb  = (unsigned*)(ws);                        // ~1.05 MB
  float2* Y      = (float2*)(ws + (size_t)(2 << 20));      // 4 MB
  uint2* bucket  = (uint2*)(ws + (size_t)(6 << 20));       // K*8 ~= 6.7 MB (ends <13M)
  int* cnt       = (int*)(ws + (size_t)(13 << 20));        // 4 MB (ends 17M)
  char* meta     = ws + (size_t)(17 << 20);                // tot/off 32 KB
  int* tot = (int*)(meta);
  int* off = (int*)(meta + 16384);
  ushort_t* xbf  = (ushort_t*)(ws + (size_t)(18 << 20));   // 1 MB (ends 19M)
  float* part    = (float*)(ws + (size_t)(2 << 20));       // KC*2MB = 16 MB (ends 18M);
  // part ALIASES Y/bucket/cnt/meta — all fully consumed before gemm runs.

  xcvt<<<512, 256, 0, stream>>>(x, xbf);
  dft_rows_x<<<dim3(NROW, 2), 1024, 0, stream>>>(x, XTb);
  count_chunks<<<NCHUNK, 1024, 0, stream>>>(midx, K, chunk, cnt);
  colscan<<<16, 256, 0, stream>>>(cnt, tot);
  scan4096<<<1, 1024, 0, stream>>>(tot, off);
  scatter2<<<NCHUNK, 1024, 0, stream>>>(midx, cre, cim, K, chunk, cnt, off, bucket);
  spmm_col<<<2048, 256, 0, stream>>>(bucket, off, tot, XTb, Y);
  dft_rows_y<<<dim3(NROW, 2), 1024, 0, stream>>>(Y, out);      // writes out2
  gemm_mfma_partial<<<dim3(64, KC), 256, 0, stream>>>(xbf, W, part);
  reduce_bias<<<512, 256, 0, stream>>>(part, b, out);          // out += b + sum(part)
}

// Round 12
// 125.061 us; speedup vs baseline: 1.1378x; 1.1244x over previous
//
#include <hip/hip_runtime.h>

// LFMA adapter: out = x@W_base^T + b + x @ (alpha * Re(ifft2(scatter(c, mask_idx))))
// Factored: never materialize Delta_W.
//   X[t,k1] = sum_m x[t,m] e^{+2pi i m k1/4096}   (fused_stage1; Hermitian k<=2048, bf16)
//   Y[t,k2] = sum_{nz} c * X[t,k1]                (bucketed sparse spmm, dot2 - R11)
//   out2[t,n] = SCALE*Re(DFT(Y row)) + b + sum(part)   (dft_rows_y epilogue-fused)
// R12: (1) gemm rewritten to m97 structure: global_load_lds(16B) staging, single-buffer
// 2-barrier loop, BK=128, pre-swizzled GLOBAL source (LDS dest must be linear), W kept
// fp32 in LDS + v_cvt_pk_bf16_f32 on fragment read. R5's reg-staged pipeline was ~39us
// (compiler re-serialized it - same failure proven in R7/R9/R10); floor is the 67MB W
// stream. (2) dft_x fused with count_chunks (independent, same blockdim). (3) partials
// bf16 (8MB, aliases dead bucket/cnt) + reduce_bias absorbed into dft_y.

#define TWO_PI 6.28318530717958647692f
constexpr int NROW = 128;
constexpr float SCALE_A = 16.0f / 16777216.0f;
constexpr int NCHUNK = 256;
constexpr int KC = 8;

typedef unsigned short ushort_t;
using short8 = __attribute__((ext_vector_type(8))) short;
using f32x4  = __attribute__((ext_vector_type(4))) float;

__device__ __forceinline__ ushort_t f2bf(float f) {
  unsigned u = __float_as_uint(f);
  u = (u + 0x7FFFu + ((u >> 16) & 1u)) >> 16;   // RNE
  return (ushort_t)u;
}

__device__ __forceinline__ unsigned cvtpk(float lo, float hi) {
  unsigned r;
  asm("v_cvt_pk_bf16_f32 %0, %1, %2" : "=v"(r) : "v"(lo), "v"(hi));
  return r;
}

__device__ __forceinline__ void gload_lds16(const void* g, void* l) {
  __builtin_amdgcn_global_load_lds(
      (const __attribute__((address_space(1))) unsigned*)g,
      (__attribute__((address_space(3))) unsigned*)l, 16, 0, 0);
}

// ---------------- fused stage 1: dft_rows_x (blocks 0..255) || count_chunks (256..511)
__global__ __launch_bounds__(1024) void fused_stage1(const float* __restrict__ x,
                                                     unsigned* __restrict__ XTb,
                                                     const int* __restrict__ idx, int K,
                                                     int chunk, int* __restrict__ cnt) {
  __shared__ __align__(16) char smem[33280];
  const int bx = blockIdx.x, tid = threadIdx.x;
  if (bx < 256) {
    // ---- dft_rows_x: t = bx&127, qi = bx>>7
    float* xs = (float*)smem;              // 4096 f
    float* br = xs + 4096;                 // 2048 f
    float* bi = br + 2048;                 // 2048 f
    float2* w64 = (float2*)(bi + 2048);    // 64 f2
    const int t = bx & 127, qi = bx >> 7;
    const float* xrow = x + (size_t)t * 4096;
#pragma unroll
    for (int l = 0; l < 4; ++l) xs[tid + 1024 * l] = xrow[tid + 1024 * l];
    if (tid < 64) {
      float s, c; __sincosf(TWO_PI * (float)tid * (1.0f / 64.0f), &s, &c);
      w64[tid] = make_float2(c, s);        // W64^j = e^{+2pi i j/64}
    }
    __syncthreads();
#pragma unroll
    for (int l = 0; l < 2; ++l) {
      int o = tid + 1024 * l, m1 = o >> 5, k1l = o & 31, k1 = qi * 32 + k1l;
      float ar = 0.f, ai = 0.f;
      for (int m2 = 0; m2 < 64; ++m2) {
        float xv = xs[m1 + (m2 << 6)];
        float2 w = w64[(m2 * k1) & 63];
        ar = fmaf(xv, w.x, ar); ai = fmaf(xv, w.y, ai);
      }
      float s, c; __sincosf((float)(m1 * k1) * (TWO_PI / 4096.0f), &s, &c);
      br[(m1 << 5) + k1l] = ar * c - ai * s;
      bi[(m1 << 5) + k1l] = ar * s + ai * c;
    }
    __syncthreads();
    {
      const int k1l = tid & 31, k2 = tid >> 5;
      const int k = qi * 32 + k1l + (k2 << 6);
      float xr = 0.f, xi = 0.f;
      for (int m1 = 0; m1 < 64; ++m1) {
        float brv = br[(m1 << 5) + k1l], biv = bi[(m1 << 5) + k1l];
        float2 w = w64[(m1 * k2) & 63];
        xr += brv * w.x - biv * w.y;
        xi += brv * w.y + biv * w.x;
      }
      XTb[(size_t)k * NROW + t] = (unsigned)f2bf(xr) | ((unsigned)f2bf(xi) << 16);
      if (qi == 0 && tid == 0) {           // k = 2048: w64^(32*m1) = (-1)^m1
        float xr2 = 0.f, xi2 = 0.f;
        for (int m1 = 0; m1 < 64; ++m1) {
          float sgn = (m1 & 1) ? -1.f : 1.f;
          xr2 = fmaf(sgn, br[m1 << 5], xr2);
          xi2 = fmaf(sgn, bi[m1 << 5], xi2);
        }
        XTb[(size_t)2048 * NROW + t] = (unsigned)f2bf(xr2) | ((unsigned)f2bf(xi2) << 16);
      }
    }
  } else {
    // ---- count_chunks: c = bx-256
    int* h = (int*)smem;
    const int c = bx - 256;
#pragma unroll
    for (int l = 0; l < 4; ++l) h[tid + 1024 * l] = 0;
    __syncthreads();
    const int j0 = c * chunk, j1 = min(j0 + chunk, K);
    for (int j = j0 + tid; j < j1; j += 1024) atomicAdd(&h[idx[j] & 4095], 1);
    __syncthreads();
#pragma unroll
    for (int l = 0; l < 4; ++l) cnt[(size_t)c * 4096 + tid + 1024 * l] = h[tid + 1024 * l];
  }
}

// ---------------- S2: per-column exclusive scan over chunks (in place) + totals
__global__ __launch_bounds__(256) void colscan(int* __restrict__ cnt, int* __restrict__ tot) {
  const int k2 = blockIdx.x * 256 + threadIdx.x;
  int run = 0;
  for (int c8 = 0; c8 < NCHUNK; c8 += 8) {
    int v[8];
#pragma unroll
    for (int i = 0; i < 8; ++i) v[i] = cnt[(size_t)(c8 + i) * 4096 + k2];
#pragma unroll
    for (int i = 0; i < 8; ++i) {
      cnt[(size_t)(c8 + i) * 4096 + k2] = run;
      run += v[i];
    }
  }
  tot[k2] = run;
}

// ---------------- B2: exclusive scan over 4096 totals (single block)
__global__ __launch_bounds__(1024) void scan4096(const int* __restrict__ count,
                                                 int* __restrict__ off) {
  __shared__ int s[4096];
  int tid = threadIdx.x;
#pragma unroll
  for (int l = 0; l < 4; ++l) s[tid + 1024 * l] = count[tid + 1024 * l];
  __syncthreads();
  for (int d = 1; d < 4096; d <<= 1) {
    int v[4];
#pragma unroll
    for (int l = 0; l < 4; ++l) {
      int i = tid + 1024 * l;
      v[l] = s[i] + ((i >= d) ? s[i - d] : 0);
    }
    __syncthreads();
#pragma unroll
    for (int l = 0; l < 4; ++l) s[tid + 1024 * l] = v[l];
    __syncthreads();
  }
#pragma unroll
  for (int l = 0; l < 4; ++l) {
    int i = tid + 1024 * l;
    off[i] = s[i] - count[i];
  }
}

// ---------------- S3: scatter with LDS-rank (no returning global atomics)
__global__ __launch_bounds__(1024) void scatter2(const int* __restrict__ idx,
                                                 const float* __restrict__ cre,
                                                 const float* __restrict__ cim, int K,
                                                 int chunk, const int* __restrict__ base,
                                                 const int* __restrict__ off,
                                                 uint2* __restrict__ bucket) {
  __shared__ int lbase[4096];
  __shared__ int lcur[4096];
  const int c = blockIdx.x, tid = threadIdx.x;
#pragma unroll
  for (int l = 0; l < 4; ++l) {
    int k2 = tid + 1024 * l;
    lbase[k2] = base[(size_t)c * 4096 + k2] + off[k2];
    lcur[k2] = 0;
  }
  __syncthreads();
  const int j0 = c * chunk, j1 = min(j0 + chunk, K);
  for (int j = j0 + tid; j < j1; j += 1024) {
    int p = idx[j];
    int k2 = p & 4095;
    int r = atomicAdd(&lcur[k2], 1);          // LDS atomic: fast
    unsigned cr = f2bf(cre[j]), ci = f2bf(cim[j]);
    bucket[lbase[k2] + r] = make_uint2((unsigned)(p >> 12) | (cr << 16), ci << 16);
  }
}

// ---------------- B4: Y[t][k2] = sum c * X[t,k1] (R11 dot2 version, unchanged)
__global__ __launch_bounds__(256, 4) void spmm_col(const uint2* __restrict__ bucket,
                                                   const int* __restrict__ off,
                                                   const int* __restrict__ count,
                                                   const unsigned* __restrict__ XTb,
                                                   float2* __restrict__ Y) {
  __shared__ float4 red[2][64];
  const int lane = threadIdx.x & 63;
  const int wid = threadIdx.x >> 6;
  const int colsel = wid >> 1, half = wid & 1;
  const int k2 = blockIdx.x * 2 + colsel;
  const int s = off[k2], n = count[k2];
  const unsigned voff = lane * 8;
  float ar0 = 0.f, ai0 = 0.f, ar1 = 0.f, ai1 = 0.f;
  for (int c = half * 64; c < n; c += 128) {
    int idx = c + lane;
    uint2 ec = (idx < n) ? bucket[s + idx] : make_uint2(0u, 0u);
#pragma unroll
    for (int g = 0; g < 64; g += 8) {
      unsigned Ap[8], Bp[8];
      uint2 xv0, xv1, xv2, xv3, xv4, xv5, xv6, xv7;
#pragma unroll
      for (int u = 0; u < 8; ++u) {
        unsigned w0 = (unsigned)__builtin_amdgcn_readlane((int)ec.x, g + u);
        unsigned w1 = (unsigned)__builtin_amdgcn_readlane((int)ec.y, g + u);
        int k1 = (int)(w0 & 0xfffu);
        unsigned cj = (k1 > 2048) ? 0x8000u : 0u;
        int r = (k1 > 2048) ? 4096 - k1 : k1;
        unsigned cr16 = w0 >> 16;
        unsigned ci16 = w1 >> 16;
        Ap[u] = cr16 | ((ci16 ^ 0x8000u ^ cj) << 16);
        Bp[u] = ci16 | ((cr16 ^ cj) << 16);
        const unsigned* p = XTb + (size_t)r * NROW;
        uint2* dst = (u == 0) ? &xv0 : (u == 1) ? &xv1 : (u == 2) ? &xv2 :
                     (u == 3) ? &xv3 : (u == 4) ? &xv4 : (u == 5) ? &xv5 :
                     (u == 6) ? &xv6 : &xv7;
        asm volatile("global_load_dwordx2 %0, %1, %2"
                     : "=v"(*dst) : "v"(voff), "s"(p) : "memory");
      }
      asm volatile("s_waitcnt vmcnt(0)"
                   : "+v"(xv0), "+v"(xv1), "+v"(xv2), "+v"(xv3),
                     "+v"(xv4), "+v"(xv5), "+v"(xv6), "+v"(xv7) :: "memory");
      __builtin_amdgcn_sched_barrier(0);
#pragma unroll
      for (int u = 0; u < 8; ++u) {
        uint2 xv = (u == 0) ? xv0 : (u == 1) ? xv1 : (u == 2) ? xv2 :
                   (u == 3) ? xv3 : (u == 4) ? xv4 : (u == 5) ? xv5 :
                   (u == 6) ? xv6 : xv7;
        asm("v_dot2_f32_bf16 %0, %1, %2, %0" : "+v"(ar0) : "v"(Ap[u]), "v"(xv.x));
        asm("v_dot2_f32_bf16 %0, %1, %2, %0" : "+v"(ai0) : "v"(Bp[u]), "v"(xv.x));
        asm("v_dot2_f32_bf16 %0, %1, %2, %0" : "+v"(ar1) : "v"(Ap[u]), "v"(xv.y));
        asm("v_dot2_f32_bf16 %0, %1, %2, %0" : "+v"(ai1) : "v"(Bp[u]), "v"(xv.y));
      }
    }
  }
  if (half == 1) red[colsel][lane] = make_float4(ar0, ai0, ar1, ai1);
  __syncthreads();
  if (half == 0) {
    float4 o = red[colsel][lane];
    ar0 += o.x; ai0 += o.y; ar1 += o.z; ai1 += o.w;
    Y[(size_t)(2 * lane) * 4096 + k2]     = make_float2(ar0, ai0);
    Y[(size_t)(2 * lane + 1) * 4096 + k2] = make_float2(ar1, ai1);
  }
}

// ---------------- base GEMM partials (m97 structure): partb[kc][128][4096] bf16.
// global_load_lds 16B staging, single-buffer 2-barrier loop, BK=128, kc=8 K-split.
// LDS dest linear (HW constraint) -> global SOURCE pre-swizzled; ds_read applies
// the same XOR. W kept fp32 in LDS; fragments cvt_pk'd to bf16 on read.
__global__ __launch_bounds__(256) void gemm_mfma_partial(const ushort_t* __restrict__ xbf,
                                                         const float* __restrict__ W,
                                                         ushort_t* __restrict__ partb) {
  __shared__ ushort_t xs[128 * 128];   // 32 KB bf16: 16 slots of 8 bf16 per row
  __shared__ float    wsf[64 * 128];   // 32 KB fp32: 16 slots of 8 fp32 per row
  const int f0 = blockIdx.x * 64;
  const int kc = blockIdx.y;
  const int tid = threadIdx.x;
  const int w = tid >> 6, lane = tid & 63;

  f32x4 acc[2][4];
#pragma unroll
  for (int i = 0; i < 2; ++i)
#pragma unroll
    for (int j = 0; j < 4; ++j) acc[i][j] = (f32x4){0.f, 0.f, 0.f, 0.f};

  const int kbeg = kc * 512;
  for (int st = 0; st < 4; ++st) {
    const int k0 = kbeg + st * 128;
    // stage x tile [128][128] bf16: wave w covers LDS bytes [w*8192, w*8192+8192)
#pragma unroll
    for (int cc = 0; cc < 8; ++cc) {
      int lb = w * 8192 + cc * 1024;           // wave-uniform LDS byte base
      int e  = (lb >> 1) + lane * 8;           // this lane's first bf16 element
      int r  = e >> 7;
      int sl = (e >> 3) & 15;
      gload_lds16(xbf + (size_t)r * 4096 + k0 + ((sl ^ (r & 15)) << 3),
                  (char*)xs + lb);
    }
    // stage W tile [64][128] fp32
#pragma unroll
    for (int cc = 0; cc < 8; ++cc) {
      int lb = w * 8192 + cc * 1024;
      int e32 = (lb >> 2) + lane * 4;          // first fp32 element
      int r = e32 >> 7;
      int g = (e32 >> 2) & 31;                 // 4-fp32 granule in row
      int s8 = g >> 1, h = g & 1;
      gload_lds16(W + (size_t)(f0 + r) * 4096 + k0 + ((s8 ^ (r & 15)) << 3) + (h << 2),
                  (char*)wsf + lb);
    }
    __syncthreads();                            // compiler drains vmcnt before barrier
#pragma unroll
    for (int kk = 0; kk < 4; ++kk) {
      int ksA = kk * 4 + (lane >> 4);
      short8 af[2], bfr[4];
#pragma unroll
      for (int mf = 0; mf < 2; ++mf) {
        int ra = w * 32 + mf * 16 + (lane & 15);
        af[mf] = *(const short8*)(&xs[ra * 128 + ((ksA ^ (ra & 15)) << 3)]);
      }
#pragma unroll
      for (int nf = 0; nf < 4; ++nf) {
        int rb = nf * 16 + (lane & 15);
        const float* bp = &wsf[rb * 128 + ((ksA ^ (rb & 15)) << 3)];
        float4 a4 = *(const float4*)bp;
        float4 b4 = *(const float4*)(bp + 4);
        union { uint4 u; short8 s; } pk;
        pk.u.x = cvtpk(a4.x, a4.y);
        pk.u.y = cvtpk(a4.z, a4.w);
        pk.u.z = cvtpk(b4.x, b4.y);
        pk.u.w = cvtpk(b4.z, b4.w);
        bfr[nf] = pk.s;
      }
#pragma unroll
      for (int mf = 0; mf < 2; ++mf)
#pragma unroll
        for (int nf = 0; nf < 4; ++nf)
          acc[mf][nf] = __builtin_amdgcn_mfma_f32_16x16x32_bf16(af[mf], bfr[nf], acc[mf][nf], 0, 0, 0);
    }
    __syncthreads();
  }
  ushort_t* pb = partb + ((size_t)kc << 19);
#pragma unroll
  for (int mf = 0; mf < 2; ++mf)
#pragma unroll
    for (int nf = 0; nf < 4; ++nf)
#pragma unroll
      for (int reg = 0; reg < 4; ++reg) {
        int row = w * 32 + mf * 16 + (lane >> 4) * 4 + reg;
        int col = f0 + nf * 16 + (lane & 15);
        pb[(size_t)row * 4096 + col] = f2bf(acc[mf][nf][reg]);
      }
}

// ---------------- Kernel C: out = SCALE*Re(DFT(Y row)) + bias + sum(bf16 partials).
// grid (128,2); block qi handles n1 residue [qi*32, qi*32+32). WRITES final out.
__global__ __launch_bounds__(1024) void dft_rows_y(const float2* __restrict__ Y,
                                                   const ushort_t* __restrict__ partb,
                                                   const float* __restrict__ bias,
                                                   float* __restrict__ out) {
  __shared__ float ysr[4096], ysi[4096];
  __shared__ float br[2048], bi[2048];
  __shared__ float2 w64[64];
  const int t = blockIdx.x, qi = blockIdx.y, tid = threadIdx.x;
  const float2* yrow = Y + (size_t)t * 4096;
#pragma unroll
  for (int l = 0; l < 4; ++l) {
    float2 v = yrow[tid + 1024 * l];
    ysr[tid + 1024 * l] = v.x; ysi[tid + 1024 * l] = v.y;
  }
  if (tid < 64) {
    float s, c; __sincosf(TWO_PI * (float)tid * (1.0f / 64.0f), &s, &c);
    w64[tid] = make_float2(c, s);
  }
  __syncthreads();
#pragma unroll
  for (int l = 0; l < 2; ++l) {
    int o = tid + 1024 * l, a = o >> 5, n1l = o & 31, n1 = qi * 32 + n1l;
    float ar = 0.f, ai = 0.f;
    for (int b = 0; b < 64; ++b) {
      float yr = ysr[a + (b << 6)], yi = ysi[a + (b << 6)];
      float2 w = w64[(n1 * b) & 63];
      ar += yr * w.x - yi * w.y;
      ai += yr * w.y + yi * w.x;
    }
    float s, c; __sincosf((float)(n1 * a) * (TWO_PI / 4096.0f), &s, &c);
    br[(a << 5) + n1l] = ar * c - ai * s;
    bi[(a << 5) + n1l] = ar * s + ai * c;
  }
  __syncthreads();
  float* orow = out + (size_t)t * 4096;
  const int n1l = tid & 31;
  const int n1 = qi * 32 + n1l;
#pragma unroll
  for (int l = 0; l < 2; ++l) {
    int n2 = (tid >> 5) + 32 * l;
    float accv = 0.f;
    for (int a = 0; a < 64; ++a) {
      float brv = br[(a << 5) + n1l], biv = bi[(a << 5) + n1l];
      float2 w = w64[(n2 * a) & 63];
      accv += brv * w.x - biv * w.y;
    }
    int o = n1 + (n2 << 6);
    float sum = accv * SCALE_A + bias[o];
#pragma unroll
    for (int i = 0; i < KC; ++i) {
      unsigned uu = partb[((size_t)i << 19) + ((size_t)t << 12) + o];
      sum += __int_as_float((int)(uu << 16));
    }
    orow[o] = sum;
  }
}

// ---------------- x -> bf16 pre-convert
__global__ __launch_bounds__(256) void xcvt(const float* __restrict__ x,
                                            ushort_t* __restrict__ xbf) {
  size_t e = ((size_t)blockIdx.x * 256 + threadIdx.x) * 4;
  float4 v = *(const float4*)(x + e);
  unsigned lo = (unsigned)f2bf(v.x) | ((unsigned)f2bf(v.y) << 16);
  unsigned hi = (unsigned)f2bf(v.z) | ((unsigned)f2bf(v.w) << 16);
  *(uint2*)(xbf + e) = make_uint2(lo, hi);
}

extern "C" void kernel_launch(void* const* d_in, const int* in_sizes, int n_in,
                              void* d_out, int out_size, void* d_ws, size_t ws_size,
                              hipStream_t stream) {
  const float* x   = (const float*)d_in[0];
  const float* W   = (const float*)d_in[1];
  const float* b   = (const float*)d_in[2];
  const float* cre = (const float*)d_in[3];
  const float* cim = (const float*)d_in[4];
  const int* midx  = (const int*)d_in[5];
  const int K = in_sizes[3];
  float* out = (float*)d_out;
  const int chunk = (K + NCHUNK - 1) / NCHUNK;

  char* ws = (char*)d_ws;
  // Layout (peak 18 MB; partb aliases dead bucket/cnt-head):
  unsigned* XTb   = (unsigned*)(ws);                             // 0..1.05M
  float2* Y       = (float2*)(ws + ((size_t)2 << 20));           // 2M..6M
  char* meta      = ws + ((size_t)6 << 20);                      // 6M..6M+64K
  int* tot = (int*)(meta);
  int* off = (int*)(meta + 16384);
  uint2* bucket   = (uint2*)(ws + ((size_t)6 << 20) + 65536);    // 6.06M..13.07M
  int* cnt        = (int*)(ws + ((size_t)13 << 20));             // 13M..17M
  ushort_t* xbf   = (ushort_t*)(ws + ((size_t)17 << 20));        // 17M..18M
  ushort_t* partb = (ushort_t*)(ws + ((size_t)6 << 20) + 131072);// 6.1M..14.5M (8MB)
  // partb written by gemm AFTER spmm consumed bucket & scatter2 consumed cnt.

  xcvt<<<512, 256, 0, stream>>>(x, xbf);
  fused_stage1<<<512, 1024, 0, stream>>>(x, XTb, midx, K, chunk, cnt);
  colscan<<<16, 256, 0, stream>>>(cnt, tot);
  scan4096<<<1, 1024, 0, stream>>>(tot, off);
  scatter2<<<NCHUNK, 1024, 0, stream>>>(midx, cre, cim, K, chunk, cnt, off, bucket);
  spmm_col<<<2048, 256, 0, stream>>>(bucket, off, tot, XTb, Y);
  gemm_mfma_partial<<<dim3(64, KC), 256, 0, stream>>>(xbf, W, partb);
  dft_rows_y<<<dim3(NROW, 2), 1024, 0, stream>>>(Y, partb, b, out);
}

// Round 13
// 111.524 us; speedup vs baseline: 1.2759x; 1.1214x over previous
//
#include <hip/hip_runtime.h>

// LFMA adapter: out = x@W_base^T + b + x @ (alpha * Re(ifft2(scatter(c, mask_idx))))
// Factored: never materialize Delta_W.
//   X[t,k1] = DFT4096(x rows)      (fused_stage1; Hermitian k<=2048, bf16, dot2 phase2)
//   Y[t,k2] = sum_nz c * X[t,k1]   (bucketed sparse spmm, dot2; Y packed bf16)
//   out = SCALE*Re(DFT(Y)) + b + sum(part)   (dft_rows_y, dot2 + fused epilogue)
// R13: (1) gemm fused INTO the spmm launch (heterogeneous blocks; single stream has no
// inter-kernel overlap) - gemm KC=4 BK=64 32KB-LDS so fused kernel keeps 5 blocks/CU;
// partb un-aliased (4MB own region). (2) both DFTs use v_dot2_f32_bf16 with packed
// bf16 twiddles/intermediates; Y stored packed bf16 (2MB). (3) xcvt absorbed into
// stage1. Bucketing: two-pass LDS-histogram ranking (R4), no global atomics.

#define TWO_PI 6.28318530717958647692f
constexpr int NROW = 128;
constexpr float SCALE_A = 16.0f / 16777216.0f;
constexpr int NCHUNK = 256;
constexpr int KC = 4;

typedef unsigned short ushort_t;
using short8 = __attribute__((ext_vector_type(8))) short;
using f32x4  = __attribute__((ext_vector_type(4))) float;

__device__ __forceinline__ ushort_t f2bf(float f) {
  unsigned u = __float_as_uint(f);
  u = (u + 0x7FFFu + ((u >> 16) & 1u)) >> 16;   // RNE
  return (ushort_t)u;
}
__device__ __forceinline__ unsigned cvtpk(float lo, float hi) {
  unsigned r;
  asm("v_cvt_pk_bf16_f32 %0, %1, %2" : "=v"(r) : "v"(lo), "v"(hi));
  return r;
}
__device__ __forceinline__ float bflo(unsigned u) { return __int_as_float((int)(u << 16)); }
__device__ __forceinline__ float bfhi(unsigned u) { return __int_as_float((int)(u & 0xffff0000u)); }
__device__ __forceinline__ void dot2(float& acc, unsigned a, unsigned b) {
  asm("v_dot2_f32_bf16 %0, %1, %2, %0" : "+v"(acc) : "v"(a), "v"(b));
}
__device__ __forceinline__ void gload_lds16(const void* g, void* l) {
  __builtin_amdgcn_global_load_lds(
      (const __attribute__((address_space(1))) unsigned*)g,
      (__attribute__((address_space(3))) unsigned*)l, 16, 0, 0);
}

// ---------------- stage 1: dft_x (0..255) || count_chunks (256..511) || xcvt (512..639)
__global__ __launch_bounds__(1024) void fused_stage1(const float* __restrict__ x,
                                                     unsigned* __restrict__ XTb,
                                                     const int* __restrict__ idx, int K,
                                                     int chunk, int* __restrict__ cnt,
                                                     ushort_t* __restrict__ xbf) {
  __shared__ __align__(16) char smem[25600];
  const int bx = blockIdx.x, tid = threadIdx.x;
  if (bx >= 512) {                         // ---- xcvt: 128 blocks, 1 float4/thread
    int i = (bx - 512) * 1024 + tid;
    float4 v = ((const float4*)x)[i];
    ((uint2*)xbf)[i] = make_uint2(cvtpk(v.x, v.y), cvtpk(v.z, v.w));
    return;
  }
  if (bx < 256) {
    // ---- dft_rows_x: t = bx&127, qi = bx>>7 (k1 residue half)
    float*    xs   = (float*)smem;             // 16384 B
    unsigned* bp   = (unsigned*)(smem + 16384);// 8192 B packed (br,bi)
    float2*   w64f = (float2*)(smem + 24576);  // 512 B
    unsigned* wA   = (unsigned*)(smem + 25088);
    unsigned* wB   = (unsigned*)(smem + 25344);
    const int t = bx & 127, qi = bx >> 7;
    const float* xrow = x + (size_t)t * 4096;
#pragma unroll
    for (int l = 0; l < 4; ++l) xs[tid + 1024 * l] = xrow[tid + 1024 * l];
    if (tid < 64) {
      float s, c; __sincosf(TWO_PI * (float)tid * (1.0f / 64.0f), &s, &c);
      w64f[tid] = make_float2(c, s);           // W64^j = e^{+2pi i j/64}
      wA[tid] = cvtpk(c, -s);
      wB[tid] = cvtpk(s, c);
    }
    __syncthreads();
    // phase 1 (fp32): B[m1][k1] for this residue half, packed store
#pragma unroll
    for (int l = 0; l < 2; ++l) {
      int o = tid + 1024 * l, m1 = o >> 5, k1l = o & 31, k1 = qi * 32 + k1l;
      float ar = 0.f, ai = 0.f;
      for (int m2 = 0; m2 < 64; ++m2) {
        float xv = xs[m1 + (m2 << 6)];
        float2 w = w64f[(m2 * k1) & 63];
        ar = fmaf(xv, w.x, ar); ai = fmaf(xv, w.y, ai);
      }
      float s, c; __sincosf((float)(m1 * k1) * (TWO_PI / 4096.0f), &s, &c);
      bp[(m1 << 5) + k1l] = cvtpk(ar * c - ai * s, ar * s + ai * c);
    }
    __syncthreads();
    // phase 2 (dot2): k = qi*32 + k1l + 64*k2
    {
      const int k1l = tid & 31, k2 = tid >> 5;
      const int k = qi * 32 + k1l + (k2 << 6);
      float xr = 0.f, xi = 0.f;
      for (int m1 = 0; m1 < 64; ++m1) {
        unsigned wi = (unsigned)((m1 * k2) & 63);
        unsigned bv = bp[(m1 << 5) + k1l];
        dot2(xr, wA[wi], bv);
        dot2(xi, wB[wi], bv);
      }
      XTb[(size_t)k * NROW + t] = cvtpk(xr, xi);
      if (qi == 0 && tid == 0) {               // k = 2048: w64^(32*m1) = (-1)^m1
        float xr2 = 0.f, xi2 = 0.f;
        for (int m1 = 0; m1 < 64; ++m1) {
          float sgn = (m1 & 1) ? -1.f : 1.f;
          unsigned bv = bp[m1 << 5];
          xr2 = fmaf(sgn, bflo(bv), xr2);
          xi2 = fmaf(sgn, bfhi(bv), xi2);
        }
        XTb[(size_t)2048 * NROW + t] = cvtpk(xr2, xi2);
      }
    }
  } else {
    // ---- count_chunks: c = bx-256
    int* h = (int*)smem;
    const int c = bx - 256;
#pragma unroll
    for (int l = 0; l < 4; ++l) h[tid + 1024 * l] = 0;
    __syncthreads();
    const int j0 = c * chunk, j1 = min(j0 + chunk, K);
    for (int j = j0 + tid; j < j1; j += 1024) atomicAdd(&h[idx[j] & 4095], 1);
    __syncthreads();
#pragma unroll
    for (int l = 0; l < 4; ++l) cnt[(size_t)c * 4096 + tid + 1024 * l] = h[tid + 1024 * l];
  }
}

// ---------------- S2: per-column exclusive scan over chunks (in place) + totals
__global__ __launch_bounds__(256) void colscan(int* __restrict__ cnt, int* __restrict__ tot) {
  const int k2 = blockIdx.x * 256 + threadIdx.x;
  int run = 0;
  for (int c8 = 0; c8 < NCHUNK; c8 += 8) {
    int v[8];
#pragma unroll
    for (int i = 0; i < 8; ++i) v[i] = cnt[(size_t)(c8 + i) * 4096 + k2];
#pragma unroll
    for (int i = 0; i < 8; ++i) {
      cnt[(size_t)(c8 + i) * 4096 + k2] = run;
      run += v[i];
    }
  }
  tot[k2] = run;
}

// ---------------- B2: exclusive scan over 4096 totals (single block)
__global__ __launch_bounds__(1024) void scan4096(const int* __restrict__ count,
                                                 int* __restrict__ off) {
  __shared__ int s[4096];
  int tid = threadIdx.x;
#pragma unroll
  for (int l = 0; l < 4; ++l) s[tid + 1024 * l] = count[tid + 1024 * l];
  __syncthreads();
  for (int d = 1; d < 4096; d <<= 1) {
    int v[4];
#pragma unroll
    for (int l = 0; l < 4; ++l) {
      int i = tid + 1024 * l;
      v[l] = s[i] + ((i >= d) ? s[i - d] : 0);
    }
    __syncthreads();
#pragma unroll
    for (int l = 0; l < 4; ++l) s[tid + 1024 * l] = v[l];
    __syncthreads();
  }
#pragma unroll
  for (int l = 0; l < 4; ++l) {
    int i = tid + 1024 * l;
    off[i] = s[i] - count[i];
  }
}

// ---------------- S3: scatter with LDS-rank (no returning global atomics)
__global__ __launch_bounds__(1024) void scatter2(const int* __restrict__ idx,
                                                 const float* __restrict__ cre,
                                                 const float* __restrict__ cim, int K,
                                                 int chunk, const int* __restrict__ base,
                                                 const int* __restrict__ off,
                                                 uint2* __restrict__ bucket) {
  __shared__ int lbase[4096];
  __shared__ int lcur[4096];
  const int c = blockIdx.x, tid = threadIdx.x;
#pragma unroll
  for (int l = 0; l < 4; ++l) {
    int k2 = tid + 1024 * l;
    lbase[k2] = base[(size_t)c * 4096 + k2] + off[k2];
    lcur[k2] = 0;
  }
  __syncthreads();
  const int j0 = c * chunk, j1 = min(j0 + chunk, K);
  for (int j = j0 + tid; j < j1; j += 1024) {
    int p = idx[j];
    int k2 = p & 4095;
    int r = atomicAdd(&lcur[k2], 1);          // LDS atomic: fast
    unsigned cr = f2bf(cre[j]), ci = f2bf(cim[j]);
    bucket[lbase[k2] + r] = make_uint2((unsigned)(p >> 12) | (cr << 16), ci << 16);
  }
}

// ---------------- fused heavy: gemm (blocks 0..255) || spmm (blocks 256..2303)
// gemm: 128x64-tile, BK=64, KC=4 K-split, global_load_lds staging, pre-swizzled src.
// spmm: R11 dot2 body; Y written packed bf16.
__global__ __launch_bounds__(256, 4) void fused_heavy(const uint2* __restrict__ bucket,
                                                      const int* __restrict__ off,
                                                      const int* __restrict__ count,
                                                      const unsigned* __restrict__ XTb,
                                                      unsigned* __restrict__ Yp,
                                                      const ushort_t* __restrict__ xbf,
                                                      const float* __restrict__ W,
                                                      ushort_t* __restrict__ partb) {
  __shared__ __align__(16) char smem[32768];
  const int tid = threadIdx.x;
  const int w = tid >> 6, lane = tid & 63;
  if (blockIdx.x >= 256) {
    // ---------------- spmm ----------------
    float4* red = (float4*)smem;            // [2][64]
    const int colsel = w >> 1, half = w & 1;
    const int k2 = (blockIdx.x - 256) * 2 + colsel;
    const int s = off[k2], n = count[k2];
    const unsigned voff = lane * 8;
    float ar0 = 0.f, ai0 = 0.f, ar1 = 0.f, ai1 = 0.f;
    for (int c = half * 64; c < n; c += 128) {
      int idx = c + lane;
      uint2 ec = (idx < n) ? bucket[s + idx] : make_uint2(0u, 0u);
#pragma unroll
      for (int g = 0; g < 64; g += 8) {
        unsigned Ap[8], Bp[8];
        uint2 xv0, xv1, xv2, xv3, xv4, xv5, xv6, xv7;
#pragma unroll
        for (int u = 0; u < 8; ++u) {
          unsigned w0 = (unsigned)__builtin_amdgcn_readlane((int)ec.x, g + u);
          unsigned w1 = (unsigned)__builtin_amdgcn_readlane((int)ec.y, g + u);
          int k1 = (int)(w0 & 0xfffu);
          unsigned cj = (k1 > 2048) ? 0x8000u : 0u;
          int r = (k1 > 2048) ? 4096 - k1 : k1;
          unsigned cr16 = w0 >> 16;
          unsigned ci16 = w1 >> 16;
          Ap[u] = cr16 | ((ci16 ^ 0x8000u ^ cj) << 16);
          Bp[u] = ci16 | ((cr16 ^ cj) << 16);
          const unsigned* p = XTb + (size_t)r * NROW;
          uint2* dst = (u == 0) ? &xv0 : (u == 1) ? &xv1 : (u == 2) ? &xv2 :
                       (u == 3) ? &xv3 : (u == 4) ? &xv4 : (u == 5) ? &xv5 :
                       (u == 6) ? &xv6 : &xv7;
          asm volatile("global_load_dwordx2 %0, %1, %2"
                       : "=v"(*dst) : "v"(voff), "s"(p) : "memory");
        }
        asm volatile("s_waitcnt vmcnt(0)"
                     : "+v"(xv0), "+v"(xv1), "+v"(xv2), "+v"(xv3),
                       "+v"(xv4), "+v"(xv5), "+v"(xv6), "+v"(xv7) :: "memory");
        __builtin_amdgcn_sched_barrier(0);
#pragma unroll
        for (int u = 0; u < 8; ++u) {
          uint2 xv = (u == 0) ? xv0 : (u == 1) ? xv1 : (u == 2) ? xv2 :
                     (u == 3) ? xv3 : (u == 4) ? xv4 : (u == 5) ? xv5 :
                     (u == 6) ? xv6 : xv7;
          dot2(ar0, Ap[u], xv.x);
          dot2(ai0, Bp[u], xv.x);
          dot2(ar1, Ap[u], xv.y);
          dot2(ai1, Bp[u], xv.y);
        }
      }
    }
    if (half == 1) red[colsel * 64 + lane] = make_float4(ar0, ai0, ar1, ai1);
    __syncthreads();
    if (half == 0) {
      float4 o = red[colsel * 64 + lane];
      ar0 += o.x; ai0 += o.y; ar1 += o.z; ai1 += o.w;
      Yp[(size_t)(2 * lane) * 4096 + k2]     = cvtpk(ar0, ai0);
      Yp[(size_t)(2 * lane + 1) * 4096 + k2] = cvtpk(ar1, ai1);
    }
  } else {
    // ---------------- gemm ----------------
    ushort_t* xs = (ushort_t*)smem;         // [128][64] bf16, 16 KB
    float* wsf = (float*)(smem + 16384);    // [64][64] fp32, 16 KB
    const int f0 = (blockIdx.x & 63) * 64;
    const int kc = blockIdx.x >> 6;
    f32x4 acc[2][4];
#pragma unroll
    for (int i = 0; i < 2; ++i)
#pragma unroll
      for (int j = 0; j < 4; ++j) acc[i][j] = (f32x4){0.f, 0.f, 0.f, 0.f};
    const int kbeg = kc * 1024;
    for (int st = 0; st < 16; ++st) {
      const int k0 = kbeg + st * 64;
      // x tile: 16 KB, 4 gload16/wave; LDS linear, global src pre-swizzled
#pragma unroll
      for (int cc = 0; cc < 4; ++cc) {
        int lb = w * 4096 + cc * 1024;
        int e = (lb >> 1) + lane * 8;
        int r = e >> 6, sl = (e >> 3) & 7;
        gload_lds16(xbf + (size_t)r * 4096 + k0 + ((sl ^ (r & 7)) << 3),
                    (char*)xs + lb);
      }
      // W tile fp32: 16 KB, 4 gload16/wave
#pragma unroll
      for (int cc = 0; cc < 4; ++cc) {
        int lb = w * 4096 + cc * 1024;
        int e32 = (lb >> 2) + lane * 4;
        int r = e32 >> 6, g = (e32 >> 2) & 15, s8 = g >> 1, h = g & 1;
        gload_lds16(W + (size_t)(f0 + r) * 4096 + k0 + ((s8 ^ (r & 7)) << 3) + (h << 2),
                    (char*)wsf + lb);
      }
      __syncthreads();
#pragma unroll
      for (int kk = 0; kk < 2; ++kk) {
        int ksA = kk * 4 + (lane >> 4);
        short8 af[2], bfr[4];
#pragma unroll
        for (int mf = 0; mf < 2; ++mf) {
          int ra = w * 32 + mf * 16 + (lane & 15);
          af[mf] = *(const short8*)(&xs[ra * 64 + ((ksA ^ (ra & 7)) << 3)]);
        }
#pragma unroll
        for (int nf = 0; nf < 4; ++nf) {
          int rb = nf * 16 + (lane & 15);
          const float* bpp = &wsf[rb * 64 + ((ksA ^ (rb & 7)) << 3)];
          float4 a4 = *(const float4*)bpp;
          float4 b4 = *(const float4*)(bpp + 4);
          union { uint4 u; short8 s; } pk;
          pk.u.x = cvtpk(a4.x, a4.y);
          pk.u.y = cvtpk(a4.z, a4.w);
          pk.u.z = cvtpk(b4.x, b4.y);
          pk.u.w = cvtpk(b4.z, b4.w);
          bfr[nf] = pk.s;
        }
#pragma unroll
        for (int mf = 0; mf < 2; ++mf)
#pragma unroll
          for (int nf = 0; nf < 4; ++nf)
            acc[mf][nf] = __builtin_amdgcn_mfma_f32_16x16x32_bf16(af[mf], bfr[nf], acc[mf][nf], 0, 0, 0);
      }
      __syncthreads();
    }
    ushort_t* pb = partb + ((size_t)kc << 19);
#pragma unroll
    for (int mf = 0; mf < 2; ++mf)
#pragma unroll
      for (int nf = 0; nf < 4; ++nf)
#pragma unroll
        for (int reg = 0; reg < 4; ++reg) {
          int row = w * 32 + mf * 16 + (lane >> 4) * 4 + reg;
          int col = f0 + nf * 16 + (lane & 15);
          pb[(size_t)row * 4096 + col] = f2bf(acc[mf][nf][reg]);
        }
  }
}

// ---------------- out = SCALE*Re(DFT(Yp row)) + bias + sum(bf16 partials). grid (128,2).
__global__ __launch_bounds__(1024) void dft_rows_y(const unsigned* __restrict__ Yp,
                                                   const ushort_t* __restrict__ partb,
                                                   const float* __restrict__ bias,
                                                   float* __restrict__ out) {
  __shared__ unsigned ys[4096];
  __shared__ unsigned bp[2048];
  __shared__ unsigned wA[64], wB[64];
  const int t = blockIdx.x, qi = blockIdx.y, tid = threadIdx.x;
  const unsigned* yrow = Yp + (size_t)t * 4096;
#pragma unroll
  for (int l = 0; l < 4; ++l) ys[tid + 1024 * l] = yrow[tid + 1024 * l];
  if (tid < 64) {
    float s, c; __sincosf(TWO_PI * (float)tid * (1.0f / 64.0f), &s, &c);
    wA[tid] = cvtpk(c, -s);
    wB[tid] = cvtpk(s, c);
  }
  __syncthreads();
  // phase 1 (dot2): B[a][n1] for this residue half, packed store
#pragma unroll
  for (int l = 0; l < 2; ++l) {
    int o = tid + 1024 * l, a = o >> 5, n1l = o & 31, n1 = qi * 32 + n1l;
    float ar = 0.f, ai = 0.f;
    for (int b = 0; b < 64; ++b) {
      unsigned yv = ys[a + (b << 6)];
      unsigned wi = (unsigned)((n1 * b) & 63);
      dot2(ar, wA[wi], yv);
      dot2(ai, wB[wi], yv);
    }
    float s, c; __sincosf((float)(n1 * a) * (TWO_PI / 4096.0f), &s, &c);
    bp[(a << 5) + n1l] = cvtpk(ar * c - ai * s, ar * s + ai * c);
  }
  __syncthreads();
  // phase 2 (dot2, real part only) + epilogue
  float* orow = out + (size_t)t * 4096;
  const int n1l = tid & 31;
  const int n1 = qi * 32 + n1l;
#pragma unroll
  for (int l = 0; l < 2; ++l) {
    int n2 = (tid >> 5) + 32 * l;
    float accv = 0.f;
    for (int a = 0; a < 64; ++a)
      dot2(accv, wA[(unsigned)((n2 * a) & 63)], bp[(a << 5) + n1l]);
    int o = n1 + (n2 << 6);
    float sum = accv * SCALE_A + bias[o];
#pragma unroll
    for (int i = 0; i < KC; ++i)
      sum += bflo((unsigned)partb[((size_t)i << 19) + ((size_t)t << 12) + o] << 0) * 0.f +
             __int_as_float((int)((unsigned)partb[((size_t)i << 19) + ((size_t)t << 12) + o] << 16));
    orow[o] = sum;
  }
}

extern "C" void kernel_launch(void* const* d_in, const int* in_sizes, int n_in,
                              void* d_out, int out_size, void* d_ws, size_t ws_size,
                              hipStream_t stream) {
  const float* x   = (const float*)d_in[0];
  const float* W   = (const float*)d_in[1];
  const float* b   = (const float*)d_in[2];
  const float* cre = (const float*)d_in[3];
  const float* cim = (const float*)d_in[4];
  const int* midx  = (const int*)d_in[5];
  const int K = in_sizes[3];
  float* out = (float*)d_out;
  const int chunk = (K + NCHUNK - 1) / NCHUNK;

  char* ws = (char*)d_ws;
  // Layout (peak 20 MB, no live aliasing):
  unsigned* XTb   = (unsigned*)(ws);                             // 0 .. 1.05M
  unsigned* Yp    = (unsigned*)(ws + ((size_t)2 << 20));         // 2M .. 4M
  ushort_t* xbf   = (ushort_t*)(ws + ((size_t)4 << 20));         // 4M .. 5M
  char* meta      = ws + ((size_t)5 << 20);                      // 5M .. 5.03M
  int* tot = (int*)(meta);
  int* off = (int*)(meta + 16384);
  uint2* bucket   = (uint2*)(ws + ((size_t)5 << 20) + 262144);   // 5.25M .. 11.7M
  int* cnt        = (int*)(ws + ((size_t)12 << 20));             // 12M .. 16M
  ushort_t* partb = (ushort_t*)(ws + ((size_t)16 << 20));        // 16M .. 20M

  fused_stage1<<<640, 1024, 0, stream>>>(x, XTb, midx, K, chunk, cnt, xbf);
  colscan<<<16, 256, 0, stream>>>(cnt, tot);
  scan4096<<<1, 1024, 0, stream>>>(tot, off);
  scatter2<<<NCHUNK, 1024, 0, stream>>>(midx, cre, cim, K, chunk, cnt, off, bucket);
  fused_heavy<<<2304, 256, 0, stream>>>(bucket, off, tot, XTb, Yp, xbf, W, partb);
  dft_rows_y<<<dim3(NROW, 2), 1024, 0, stream>>>(Yp, partb, b, out);
}